// Round 20
// baseline (218.891 us; speedup 1.0000x reference)
//
#include <hip/hip_runtime.h>
#include <hip/hip_fp16.h>

#define NEG_SLOPE 0.2f

typedef unsigned int uint;
typedef unsigned short ushort;
typedef __attribute__((ext_vector_type(8))) short bf16x8;
typedef __attribute__((ext_vector_type(4))) float f32x4;
typedef __attribute__((ext_vector_type(2))) float f32x2;

__device__ __forceinline__ uint pack_bf16x2(float a, float b) {
    uint ba = __float_as_uint(a);
    uint bb = __float_as_uint(b);
    uint ra = (ba + 0x7FFFu + ((ba >> 16) & 1u)) >> 16;
    uint rb = (bb + 0x7FFFu + ((bb >> 16) & 1u)) >> 16;
    return ra | (rb << 16);
}

__device__ __forceinline__ ushort bf16_rne(float v) {
    uint b = __float_as_uint(v);
    return (ushort)((b + 0x7FFFu + ((b >> 16) & 1u)) >> 16);
}

__device__ __forceinline__ f32x2 unpack2(uint u) {
    f32x2 r;
    r.x = __uint_as_float(u << 16);
    r.y = __uint_as_float(u & 0xFFFF0000u);
    return r;
}

__device__ __forceinline__ uint pack_sw(int s, float w) {
    return ((uint)s << 16) | (uint)__half_as_ushort(__float2half_rn(w));
}

__device__ __forceinline__ int sw_src(uint u) { return (int)(u >> 16); }
__device__ __forceinline__ float sw_w(uint u) {
    return __half2float(__ushort_as_half((ushort)(u & 0xFFFFu)));
}

// ---------------- CSR build (XCD-local sharded histogram) ----------------
// Shard c = ACTUAL XCD id (s_getreg HW_REG_XCC_ID) -> shard counter lines
// live in the issuing XCD's L2 regardless of dispatch policy. c is stored
// in rank's high bits so fill replays the exact shard. Correct for ANY c.

__global__ void zero_ints(int* __restrict__ p, int n) {
    int i = blockIdx.x * 256 + threadIdx.x;
    if (i < n) p[i] = 0;
}

__global__ void hist_kernel(const int* __restrict__ dst, int* __restrict__ deg8,
                            int* __restrict__ rankc, int E, int N) {
    int i = blockIdx.x * 256 + threadIdx.x;
    if (i < E) {
        int c = __builtin_amdgcn_s_getreg(63508) & 7;  // HW_REG_XCC_ID (id=20,sz=32)
        int r = atomicAdd(&deg8[c * N + dst[i]], 1);
        rankc[i] = (c << 24) | r;
    }
}

// per-node prefix over the 8 shards (in place: deg8 -> shard base), total -> deg
__global__ __launch_bounds__(256) void base8_kernel(int* __restrict__ deg8,
                                                    int* __restrict__ deg, int N) {
    int i = blockIdx.x * 256 + threadIdx.x;
    if (i >= N) return;
    int run = 0;
#pragma unroll
    for (int c = 0; c < 8; ++c) {
        int v = deg8[c * N + i];
        deg8[c * N + i] = run;
        run += v;
    }
    deg[i] = run;
}

#define SCAN_CH 2048

__global__ __launch_bounds__(256) void scan_blocksum(const int* __restrict__ deg,
                                                     int* __restrict__ bsum, int N) {
    int blk = blockIdx.x, t = threadIdx.x;
    int base = blk * SCAN_CH;
    int s = 0;
#pragma unroll
    for (int i = 0; i < SCAN_CH / 256; ++i) {
        int idx = base + t + i * 256;
        if (idx < N) s += deg[idx];
    }
#pragma unroll
    for (int off = 1; off < 64; off <<= 1) s += __shfl_xor(s, off);
    __shared__ int wt[4];
    if ((t & 63) == 0) wt[t >> 6] = s;
    __syncthreads();
    if (t == 0) bsum[blk] = wt[0] + wt[1] + wt[2] + wt[3];
}

__global__ void scan_bsum(const int* __restrict__ bsum, int* __restrict__ boff, int nb) {
    int t = threadIdx.x;
    int orig = (t < nb) ? bsum[t] : 0;
    int v = orig;
#pragma unroll
    for (int off = 1; off < 64; off <<= 1) {
        int u = __shfl_up(v, off);
        if (t >= off) v += u;
    }
    if (t < nb) boff[t] = v - orig;
}

__global__ __launch_bounds__(256) void scan_write(const int* __restrict__ deg,
                                                  const int* __restrict__ boff,
                                                  int* __restrict__ rowptr, int N) {
    int blk = blockIdx.x, t = threadIdx.x;
    int base = blk * SCAN_CH + t * 8;
    int v[8];
    int s = 0;
#pragma unroll
    for (int r = 0; r < 8; ++r) {
        int idx = base + r;
        v[r] = (idx < N) ? deg[idx] : 0;
        s += v[r];
    }
    int lane = t & 63, wid = t >> 6;
    int p = s;
#pragma unroll
    for (int off = 1; off < 64; off <<= 1) {
        int u = __shfl_up(p, off);
        if (lane >= off) p += u;
    }
    __shared__ int wtot[4];
    if (lane == 63) wtot[wid] = p;
    __syncthreads();
    int run = boff[blk];
    for (int w = 0; w < wid; ++w) run += wtot[w];
    run += p - s;
#pragma unroll
    for (int r = 0; r < 8; ++r) {
        int idx = base + r;
        if (idx < N) {
            rowptr[idx] = run;
            run += v[r];
            if (idx == N - 1) rowptr[N] = run;
        }
    }
}

// scatter: pos = rowptr[d] + shard_base[c][d] + within-shard rank
__global__ void fill_kernel(const int* __restrict__ src, const int* __restrict__ dst,
                            const int* __restrict__ rowptr, const int* __restrict__ rankc,
                            const int* __restrict__ base8,
                            int* __restrict__ csrc, int E, int N) {
    int i = blockIdx.x * 256 + threadIdx.x;
    if (i < E) {
        int rc = rankc[i];
        int c = rc >> 24;
        int r = rc & 0xFFFFFF;
        int d = dst[i];
        __builtin_nontemporal_store(src[i],
                                    csrc + rowptr[d] + base8[c * N + d] + r);
    }
}

// -------- fused prep: fp32->bf16 cvt + 3x W-fragment pack --------
// frag[ct][kt][lane][j] = W[kt*32 + (lane>>4)*8 + j][ct*16 + (lane&15)]

template <int OUTF>
__device__ __forceinline__ void wpack_body(const float* __restrict__ W,
                                           ushort* __restrict__ wfrag, int idx) {
    constexpr int TOT = (OUTF / 16) * 4 * 64;
    if (idx >= TOT) return;
    int lane = idx & 63;
    int kt = (idx >> 6) & 3;
    int ct = idx >> 8;
    int col = ct * 16 + (lane & 15);
    int k0 = kt * 32 + (lane >> 4) * 8;
    uint4 q;
    q.x = pack_bf16x2(W[(k0 + 0) * OUTF + col], W[(k0 + 1) * OUTF + col]);
    q.y = pack_bf16x2(W[(k0 + 2) * OUTF + col], W[(k0 + 3) * OUTF + col]);
    q.z = pack_bf16x2(W[(k0 + 4) * OUTF + col], W[(k0 + 5) * OUTF + col]);
    q.w = pack_bf16x2(W[(k0 + 6) * OUTF + col], W[(k0 + 7) * OUTF + col]);
    ((uint4*)wfrag)[idx] = q;
}

__global__ __launch_bounds__(256) void prep_kernel(const float* __restrict__ X,
                                                   ushort* __restrict__ Xb, int n8,
                                                   int cvtblocks,
                                                   const float* __restrict__ W1,
                                                   ushort* __restrict__ wf1,
                                                   const float* __restrict__ W2,
                                                   ushort* __restrict__ wf2,
                                                   const float* __restrict__ W3,
                                                   ushort* __restrict__ wf3) {
    int b = blockIdx.x;
    int t = threadIdx.x;
    if (b < cvtblocks) {
        int i = b * 256 + t;
        if (i >= n8) return;
        const float4* xp = (const float4*)X + (size_t)i * 2;
        float4 v0 = xp[0], v1 = xp[1];
        uint4 q;
        q.x = pack_bf16x2(v0.x, v0.y);
        q.y = pack_bf16x2(v0.z, v0.w);
        q.z = pack_bf16x2(v1.x, v1.y);
        q.w = pack_bf16x2(v1.z, v1.w);
        ((uint4*)Xb)[i] = q;
    } else if (b < cvtblocks + 8) {
        wpack_body<128>(W1, wf1, (b - cvtblocks) * 256 + t);
    } else if (b < cvtblocks + 16) {
        wpack_body<128>(W2, wf2, (b - cvtblocks - 8) * 256 + t);
    } else {
        wpack_body<32>(W3, wf3, (b - cvtblocks - 16) * 256 + t);
    }
}

// -------- MFMA GEMM: Yb[N,OUTF] (bf16) = Xb[N,128] @ W + fused el/er --------

template <int OUTF>
__global__ __launch_bounds__(256) void gemm_mfma_kernel(const ushort* __restrict__ Xb,
                                                        const ushort* __restrict__ wfrag,
                                                        ushort* __restrict__ Yb,
                                                        const float* __restrict__ as_,
                                                        const float* __restrict__ ad_,
                                                        float* __restrict__ el,
                                                        float* __restrict__ er, int N) {
    constexpr int H = OUTF / 32;
    constexpr int NCT = OUTF / 16;
    int lane = threadIdx.x & 63;
    int wv = threadIdx.x >> 6;
    int r0 = blockIdx.x * 64 + wv * 16;
    if (r0 >= N) return;
    int lrow = lane & 15;
    int lk8 = lane >> 4;

    bf16x8 afrag[4];
    {
        int arow = min(r0 + lrow, N - 1);
        const ushort* xr = Xb + (size_t)arow * 128;
#pragma unroll
        for (int kt = 0; kt < 4; ++kt)
            afrag[kt] = *(const bf16x8*)(xr + kt * 32 + lk8 * 8);
    }

    float pel[H][4];
    float prr[H][4];
#pragma unroll
    for (int h = 0; h < H; ++h)
#pragma unroll
        for (int j = 0; j < 4; ++j) { pel[h][j] = 0.f; prr[h][j] = 0.f; }

    const bf16x8* wf = (const bf16x8*)wfrag;
#pragma unroll
    for (int ct = 0; ct < NCT; ++ct) {
        f32x4 acc = {0.f, 0.f, 0.f, 0.f};
#pragma unroll
        for (int kt = 0; kt < 4; ++kt) {
            bf16x8 b = wf[(ct * 4 + kt) * 64 + lane];
            acc = __builtin_amdgcn_mfma_f32_16x16x32_bf16(afrag[kt], b, acc, 0, 0, 0);
        }
        int col = ct * 16 + lrow;
        int h = (H == 1) ? 0 : (ct >> 1);
        float asc = as_[col], adc = ad_[col];
#pragma unroll
        for (int j = 0; j < 4; ++j) {
            int row = r0 + lk8 * 4 + j;
            float v = acc[j];
            if (row < N) Yb[(size_t)row * OUTF + col] = bf16_rne(v);
            pel[h][j] = fmaf(v, asc, pel[h][j]);
            prr[h][j] = fmaf(v, adc, prr[h][j]);
        }
    }

#pragma unroll
    for (int h = 0; h < H; ++h)
#pragma unroll
        for (int j = 0; j < 4; ++j) {
            float pe = pel[h][j], pr = prr[h][j];
#pragma unroll
            for (int off = 1; off < 16; off <<= 1) {
                pe += __shfl_xor(pe, off);
                pr += __shfl_xor(pr, off);
            }
            if (lrow == 0) {
                int row = r0 + lk8 * 4 + j;
                if (row < N) {
                    el[row * H + h] = pe;
                    er[row * H + h] = pr;
                }
            }
        }
}

// ---------------- aggregation (H=4, bf16 feat -> bf16 out) ----------------
// 1-deep software pipeline: next batch's csrc + el gathers issue before the
// current batch's bpermute/gather/fma block.

template <bool DOELU>
__global__ __launch_bounds__(256) void agg4_kernel(const ushort* __restrict__ featb,
                                                   const float* __restrict__ el,
                                                   const float* __restrict__ er,
                                                   const int* __restrict__ rowptr,
                                                   const int* __restrict__ csrc,
                                                   const float* __restrict__ bias,
                                                   ushort* __restrict__ outb, int N) {
    int lane = threadIdx.x & 63;
    int node = blockIdx.x * 4 + (threadIdx.x >> 6);
    if (node >= N) return;
    int row0 = __builtin_amdgcn_readfirstlane(rowptr[node]);
    int row1 = __builtin_amdgcn_readfirstlane(rowptr[node + 1]);

    int qe = lane >> 2;
    int qh = lane & 3;
    float ern = er[node * 4 + qh];

    int g = lane >> 4;
    int li = lane & 15;
    int h = li >> 2;
    int ib = (g << 4) + (h << 2);

    float dacc = 0.f;
    f32x2 acc2[4];
#pragma unroll
    for (int r = 0; r < 4; ++r) acc2[r] = (f32x2){0.f, 0.f};

    // pipeline prologue: batch 0 loads
    int e0 = row0 + qe;
    bool v = e0 < row1;
    int s = v ? csrc[e0] : 0;
    float elv = v ? el[s * 4 + qh] : 0.f;

    for (int base = row0; base < row1; base += 16) {
        uint u = 0;
        if (v) {
            float tt = elv + ern;
            tt = tt > 0.f ? tt : NEG_SLOPE * tt;
            float w = __expf(tt);
            dacc += w;
            u = pack_sw(s, w);
        }
        // prefetch next batch (loads in flight during gather/fma below)
        int en = base + 16 + qe;
        bool vn = en < row1;
        int sn = vn ? csrc[en] : 0;
        float elvn = vn ? el[sn * 4 + qh] : 0.f;

        uint u0 = (uint)__builtin_amdgcn_ds_bpermute(ib, (int)u);
        uint u1 = (uint)__builtin_amdgcn_ds_bpermute(ib + 64, (int)u);
        uint u2 = (uint)__builtin_amdgcn_ds_bpermute(ib + 128, (int)u);
        uint u3 = (uint)__builtin_amdgcn_ds_bpermute(ib + 192, (int)u);
        uint4 U0 = *(const uint4*)(featb + (size_t)sw_src(u0) * 128 + li * 8);
        uint4 U1 = *(const uint4*)(featb + (size_t)sw_src(u1) * 128 + li * 8);
        uint4 U2 = *(const uint4*)(featb + (size_t)sw_src(u2) * 128 + li * 8);
        uint4 U3 = *(const uint4*)(featb + (size_t)sw_src(u3) * 128 + li * 8);
        float w0 = sw_w(u0), w1 = sw_w(u1), w2 = sw_w(u2), w3 = sw_w(u3);
        acc2[0] = unpack2(U0.x) * w0 + acc2[0];
        acc2[1] = unpack2(U0.y) * w0 + acc2[1];
        acc2[2] = unpack2(U0.z) * w0 + acc2[2];
        acc2[3] = unpack2(U0.w) * w0 + acc2[3];
        acc2[0] = unpack2(U1.x) * w1 + acc2[0];
        acc2[1] = unpack2(U1.y) * w1 + acc2[1];
        acc2[2] = unpack2(U1.z) * w1 + acc2[2];
        acc2[3] = unpack2(U1.w) * w1 + acc2[3];
        acc2[0] = unpack2(U2.x) * w2 + acc2[0];
        acc2[1] = unpack2(U2.y) * w2 + acc2[1];
        acc2[2] = unpack2(U2.z) * w2 + acc2[2];
        acc2[3] = unpack2(U2.w) * w2 + acc2[3];
        acc2[0] = unpack2(U3.x) * w3 + acc2[0];
        acc2[1] = unpack2(U3.y) * w3 + acc2[1];
        acc2[2] = unpack2(U3.z) * w3 + acc2[2];
        acc2[3] = unpack2(U3.w) * w3 + acc2[3];

        v = vn; s = sn; elv = elvn;
    }

#pragma unroll
    for (int r = 0; r < 4; ++r) {
        acc2[r].x += __shfl_xor(acc2[r].x, 16);
        acc2[r].y += __shfl_xor(acc2[r].y, 16);
        acc2[r].x += __shfl_xor(acc2[r].x, 32);
        acc2[r].y += __shfl_xor(acc2[r].y, 32);
    }
#pragma unroll
    for (int off = 4; off < 64; off <<= 1) dacc += __shfl_xor(dacc, off);
    float d = __int_as_float(
        __builtin_amdgcn_ds_bpermute((li >> 2) << 2, __float_as_int(dacc)));

    if (lane < 16) {
        float inv = (row1 > row0) ? 1.f / d : 0.f;
        const float4* bv = (const float4*)bias + li * 2;
        float4 b0 = bv[0], b1 = bv[1];
        float o[8];
        o[0] = acc2[0].x * inv + b0.x;
        o[1] = acc2[0].y * inv + b0.y;
        o[2] = acc2[1].x * inv + b0.z;
        o[3] = acc2[1].y * inv + b0.w;
        o[4] = acc2[2].x * inv + b1.x;
        o[5] = acc2[2].y * inv + b1.y;
        o[6] = acc2[3].x * inv + b1.z;
        o[7] = acc2[3].y * inv + b1.w;
        if (DOELU) {
#pragma unroll
            for (int r = 0; r < 8; ++r) o[r] = o[r] > 0.f ? o[r] : __expf(o[r]) - 1.f;
        }
        uint4 q;
        q.x = pack_bf16x2(o[0], o[1]);
        q.y = pack_bf16x2(o[2], o[3]);
        q.z = pack_bf16x2(o[4], o[5]);
        q.w = pack_bf16x2(o[6], o[7]);
        *(uint4*)(outb + (size_t)node * 128 + li * 8) = q;
    }
}

// ---------------- aggregation (H=1, bf16 feat -> fp32 out) ----------------

__global__ __launch_bounds__(256) void agg1_kernel(const ushort* __restrict__ featb,
                                                   const float* __restrict__ el,
                                                   const float* __restrict__ er,
                                                   const int* __restrict__ rowptr,
                                                   const int* __restrict__ csrc,
                                                   const float* __restrict__ bias,
                                                   float* __restrict__ out, int N) {
    int lane = threadIdx.x & 63;
    int node = blockIdx.x * 4 + (threadIdx.x >> 6);
    if (node >= N) return;
    int row0 = __builtin_amdgcn_readfirstlane(rowptr[node]);
    int row1 = __builtin_amdgcn_readfirstlane(rowptr[node + 1]);

    float ern = er[node];
    int g = lane >> 3;
    int li = lane & 7;

    float dacc = 0.f;
    f32x2 acc2[2];
    acc2[0] = (f32x2){0.f, 0.f};
    acc2[1] = (f32x2){0.f, 0.f};

    for (int base = row0; base < row1; base += 64) {
        int e = base + lane;
        uint u = 0;
        if (e < row1) {
            int s = csrc[e];
            float t0 = el[s] + ern;
            t0 = t0 > 0.f ? t0 : NEG_SLOPE * t0;
            float w0 = __expf(t0);
            dacc += w0;
            u = pack_sw(s, w0);
        }
        int cnt = min(row1 - base, 64);
        int iters = (cnt + 7) >> 3;
        int it = 0;
        for (; it + 1 < iters; it += 2) {
            int idxA = ((it << 3) + g) << 2;
            int idxB = (((it + 1) << 3) + g) << 2;
            uint uA = (uint)__builtin_amdgcn_ds_bpermute(idxA, (int)u);
            uint uB = (uint)__builtin_amdgcn_ds_bpermute(idxB, (int)u);
            uint2 UA = *(const uint2*)(featb + (size_t)sw_src(uA) * 32 + li * 4);
            uint2 UB = *(const uint2*)(featb + (size_t)sw_src(uB) * 32 + li * 4);
            float wA = sw_w(uA), wB = sw_w(uB);
            acc2[0] = unpack2(UA.x) * wA + acc2[0];
            acc2[1] = unpack2(UA.y) * wA + acc2[1];
            acc2[0] = unpack2(UB.x) * wB + acc2[0];
            acc2[1] = unpack2(UB.y) * wB + acc2[1];
        }
        if (it < iters) {
            int idx = ((it << 3) + g) << 2;
            uint uS = (uint)__builtin_amdgcn_ds_bpermute(idx, (int)u);
            uint2 U = *(const uint2*)(featb + (size_t)sw_src(uS) * 32 + li * 4);
            float wS = sw_w(uS);
            acc2[0] = unpack2(U.x) * wS + acc2[0];
            acc2[1] = unpack2(U.y) * wS + acc2[1];
        }
    }

#pragma unroll
    for (int r = 0; r < 2; ++r) {
        acc2[r].x += __shfl_xor(acc2[r].x, 8);
        acc2[r].y += __shfl_xor(acc2[r].y, 8);
        acc2[r].x += __shfl_xor(acc2[r].x, 16);
        acc2[r].y += __shfl_xor(acc2[r].y, 16);
        acc2[r].x += __shfl_xor(acc2[r].x, 32);
        acc2[r].y += __shfl_xor(acc2[r].y, 32);
    }
#pragma unroll
    for (int off = 1; off < 64; off <<= 1) dacc += __shfl_xor(dacc, off);

    if (lane < 8) {
        float inv = (row1 > row0) ? 1.f / dacc : 0.f;
        float4 b0 = ((const float4*)bias)[lane];
        float4 q;
        q.x = acc2[0].x * inv + b0.x;
        q.y = acc2[0].y * inv + b0.y;
        q.z = acc2[1].x * inv + b0.z;
        q.w = acc2[1].y * inv + b0.w;
        ((float4*)(out + (size_t)node * 32))[lane] = q;
    }
}

// ---------------- host ----------------

extern "C" void kernel_launch(void* const* d_in, const int* in_sizes, int n_in,
                              void* d_out, int out_size, void* d_ws, size_t ws_size,
                              hipStream_t stream) {
    const float* features = (const float*)d_in[0];
    const int* esrc = (const int*)d_in[1];
    const int* edst = (const int*)d_in[2];
    const float* W1 = (const float*)d_in[3];
    const float* a1s = (const float*)d_in[4];
    const float* a1d = (const float*)d_in[5];
    const float* b1 = (const float*)d_in[6];
    const float* W2 = (const float*)d_in[7];
    const float* a2s = (const float*)d_in[8];
    const float* a2d = (const float*)d_in[9];
    const float* b2 = (const float*)d_in[10];
    const float* W3 = (const float*)d_in[11];
    const float* a3s = (const float*)d_in[12];
    const float* a3d = (const float*)d_in[13];
    const float* b3 = (const float*)d_in[14];

    int N = in_sizes[0] / 128;
    int E = in_sizes[1];
    int nb = (N + SCAN_CH - 1) / SCAN_CH;

    char* base = (char*)d_ws;
    size_t off = 0;
    auto nxt = [&](size_t bytes) {
        void* p = base + off;
        off += (bytes + 255) & ~(size_t)255;
        return p;
    };
    ushort* Xb = (ushort*)nxt((size_t)N * 128 * 2);   // bf16 features (layer-1 input)
    ushort* Yb = (ushort*)nxt((size_t)N * 128 * 2);   // gemm out / agg4 in
    ushort* Bb = (ushort*)nxt((size_t)N * 128 * 2);   // agg4 out / gemm in
    ushort* Y3b = (ushort*)nxt((size_t)N * 32 * 2);   // gemm32 out
    float* el = (float*)nxt((size_t)N * 4 * 4);
    float* er = (float*)nxt((size_t)N * 4 * 4);
    int* deg8 = (int*)nxt((size_t)N * 8 * 4);         // sharded counters -> shard bases
    int* deg = (int*)nxt((size_t)N * 4);
    int* rowptr = (int*)nxt((size_t)(N + 1) * 4);
    int* csrc = (int*)nxt((size_t)E * 4);
    int* rankc = (int*)nxt((size_t)E * 4);
    int* bsum = (int*)nxt((size_t)(nb + 1) * 4);
    int* boff = (int*)nxt((size_t)(nb + 1) * 4);
    ushort* wf1 = (ushort*)nxt(16384 * 2);
    ushort* wf2 = (ushort*)nxt(16384 * 2);
    ushort* wf3 = (ushort*)nxt(4096 * 2);

    int gemm_grid = (N + 63) / 64;
    int n8 = N * 16;
    int cvtblocks = (n8 + 255) / 256;
    int eblocks = (E + 255) / 256;

    // CSR build + input conversions
    zero_ints<<<(N * 8 + 255) / 256, 256, 0, stream>>>(deg8, N * 8);
    hist_kernel<<<eblocks, 256, 0, stream>>>(edst, deg8, rankc, E, N);
    prep_kernel<<<cvtblocks + 18, 256, 0, stream>>>(features, Xb, n8, cvtblocks,
                                                    W1, wf1, W2, wf2, W3, wf3);
    base8_kernel<<<(N + 255) / 256, 256, 0, stream>>>(deg8, deg, N);
    scan_blocksum<<<nb, 256, 0, stream>>>(deg, bsum, N);
    scan_bsum<<<1, 64, 0, stream>>>(bsum, boff, nb);
    scan_write<<<nb, 256, 0, stream>>>(deg, boff, rowptr, N);
    fill_kernel<<<eblocks, 256, 0, stream>>>(esrc, edst, rowptr, rankc, deg8,
                                             csrc, E, N);

    // layer 1: 128 -> 4x32, ELU
    gemm_mfma_kernel<128><<<gemm_grid, 256, 0, stream>>>(Xb, wf1, Yb, a1s, a1d, el, er, N);
    agg4_kernel<true><<<(N + 3) / 4, 256, 0, stream>>>(Yb, el, er, rowptr, csrc, b1, Bb, N);

    // layer 2: 128 -> 4x32, ELU
    gemm_mfma_kernel<128><<<gemm_grid, 256, 0, stream>>>(Bb, wf2, Yb, a2s, a2d, el, er, N);
    agg4_kernel<true><<<(N + 3) / 4, 256, 0, stream>>>(Yb, el, er, rowptr, csrc, b2, Bb, N);

    // layer 3: 128 -> 1x32, no ELU, mean over 1 head = identity
    gemm_mfma_kernel<32><<<gemm_grid, 256, 0, stream>>>(Bb, wf3, Y3b, a3s, a3d, el, er, N);
    agg1_kernel<<<(N + 3) / 4, 256, 0, stream>>>(Y3b, el, er, rowptr, csrc, b3,
                                                 (float*)d_out, N);
}